// Round 18
// baseline (175.679 us; speedup 1.0000x reference)
//
#include <hip/hip_runtime.h>
#include <hip/hip_bf16.h>

// HardgroupAttention: B=4, N=1024, C=384, heads=12, hd=32, GP=20.
// R11 recompute pipeline + issue-early staging in the attention sweeps.
// conv3 -> wgp_fuse + group argmax (fp64 exact) -> gemm_qkv (128x64 dbuf,
// Q pre-scaled SCALE*log2e) -> score3 (2 QK^T MFMA sweeps, issue-early K
// staging, exp2) -> vsplit (colinv + V'=V*colinv bf16 hi/lo transposed) ->
// pv3 (recompute S, PV MFMA, issue-early K+V staging, *rinv) -> gemm_proj.

#define B_    4
#define N_    1024
#define C_    384
#define H3_   1152
#define NH_   12
#define HD_   32
#define GP_   20
#define BH_   48
#define QSCALE 0.2550029971791444f   // (hd^-0.5) * log2(e)

typedef __attribute__((ext_vector_type(8))) short bf16x8;
typedef __attribute__((ext_vector_type(4))) float f32x4;

static __device__ __forceinline__ unsigned short f2bf(float x) {
  union { float f; unsigned u; } v; v.f = x;
  unsigned r = v.u + 0x7fff + ((v.u >> 16) & 1);   // RNE
  return (unsigned short)(r >> 16);
}
static __device__ __forceinline__ float bf2f(unsigned short h) {
  union { unsigned u; float f; } v; v.u = ((unsigned)h) << 16;
  return v.f;
}

// ---------------- conv3: split x / Wqkv / Wproj into bf16 hi/lo -------------
__global__ __launch_bounds__(256) void conv3(const float* __restrict__ x,
                                             const float* __restrict__ wq,
                                             const float* __restrict__ wp,
                                             unsigned short* __restrict__ xh,
                                             unsigned short* __restrict__ xl,
                                             unsigned short* __restrict__ wqh,
                                             unsigned short* __restrict__ wql,
                                             unsigned short* __restrict__ wph,
                                             unsigned short* __restrict__ wpl) {
  const int NX = (4096 * C_) / 4, NQ = (H3_ * C_) / 4, NP = (C_ * C_) / 4;
  int idx = blockIdx.x * 256 + threadIdx.x;
  const float* src; unsigned short *dh, *dl; int o;
  if (idx < NX)            { src = x;  dh = xh;  dl = xl;  o = idx; }
  else if (idx < NX + NQ)  { src = wq; dh = wqh; dl = wql; o = idx - NX; }
  else if (idx < NX + NQ + NP) { src = wp; dh = wph; dl = wpl; o = idx - NX - NQ; }
  else return;
  float4 v = *(const float4*)(src + (size_t)o * 4);
  float a[4] = {v.x, v.y, v.z, v.w};
  unsigned short h[4], lo[4];
  #pragma unroll
  for (int i = 0; i < 4; ++i) { h[i] = f2bf(a[i]); lo[i] = f2bf(a[i] - bf2f(h[i])); }
  uint2 ph = {(unsigned)h[0]  | ((unsigned)h[1]  << 16),
              (unsigned)h[2]  | ((unsigned)h[3]  << 16)};
  uint2 pl = {(unsigned)lo[0] | ((unsigned)lo[1] << 16),
              (unsigned)lo[2] | ((unsigned)lo[3] << 16)};
  *(uint2*)(dh + (size_t)o * 4) = ph;
  *(uint2*)(dl + (size_t)o * 4) = pl;
}

// ---------------- M[g][c] = sum_j Wgp[g][j] * Wqkv[j][c]  (fp64) ------------
__global__ __launch_bounds__(256) void wgp_fuse(const float* __restrict__ Wqkv,
                                                const float* __restrict__ Wgp,
                                                double* __restrict__ M) {
  int idx = blockIdx.x * 256 + threadIdx.x;
  if (idx >= GP_ * C_) return;
  int g = idx / C_, c = idx % C_;
  double acc = 0.0;
  for (int j = 0; j < C_; ++j)
    acc += (double)Wgp[g * C_ + j] * (double)Wqkv[(size_t)j * C_ + c];
  M[idx] = acc;
}

// ---------------- group argmax from exact x (fp64, vectorized loads) --------
__global__ __launch_bounds__(320) void group_assign2(const float* __restrict__ x,
                                                     const double* __restrict__ M,
                                                     int* __restrict__ group) {
  __shared__ double sc[16][GP_];
  int tid = threadIdx.x;
  int r = tid / GP_, g = tid % GP_;
  int n = blockIdx.x * 16 + r;
  const float* row = x + (size_t)n * C_;
  const double* w = M + (size_t)g * C_;
  double acc = 0.0;
  #pragma unroll 4
  for (int c = 0; c < C_; c += 4) {
    float4 xv = *(const float4*)(row + c);
    double2 w0 = *(const double2*)(w + c);
    double2 w1 = *(const double2*)(w + c + 2);
    acc += (double)xv.x * w0.x + (double)xv.y * w0.y +
           (double)xv.z * w1.x + (double)xv.w * w1.y;
  }
  sc[r][g] = acc;
  __syncthreads();
  if (g == 0) {
    int best = 0; double bv = sc[r][0];
    #pragma unroll
    for (int j = 1; j < GP_; ++j)
      if (sc[r][j] > bv) { bv = sc[r][j]; best = j; }
    group[n] = best;
  }
}

// ---------------- gemm_qkv: 128x64 tile, dbuf LDS, async-stage split --------
__global__ __launch_bounds__(256) void gemm_qkv(
    const unsigned short* __restrict__ Ah_g, const unsigned short* __restrict__ Al_g,
    const unsigned short* __restrict__ Bh_g, const unsigned short* __restrict__ Bl_g,
    unsigned short* __restrict__ Qh, unsigned short* __restrict__ Ql,
    unsigned short* __restrict__ Kh, unsigned short* __restrict__ Kl,
    float* __restrict__ Vf) {
  __shared__ __align__(16) unsigned short sAh[2][128 * 32];
  __shared__ __align__(16) unsigned short sAl[2][128 * 32];
  __shared__ __align__(16) unsigned short sBh[2][64 * 32];
  __shared__ __align__(16) unsigned short sBl[2][64 * 32];
  int tid = threadIdx.x;
  int l = tid & 63, w = tid >> 6;
  int lanelo = l & 15, g16 = l >> 4;
  int wr = w >> 1, wc = w & 1;
  int flat = blockIdx.x;
  int swz = (flat & 7) * 72 + (flat >> 3);   // 576 = 8*72, bijective
  int bm = swz / 18, bn = swz % 18;

  int ra = tid >> 2, c4 = tid & 3;
  const unsigned short* gAh0 = Ah_g + (size_t)(bm * 128 + ra) * C_ + c4 * 8;
  const unsigned short* gAl0 = Al_g + (size_t)(bm * 128 + ra) * C_ + c4 * 8;
  const unsigned short* gBh0 = Bh_g + (size_t)(bn * 64 + ra) * C_ + c4 * 8;
  const unsigned short* gBl0 = Bl_g + (size_t)(bn * 64 + ra) * C_ + c4 * 8;
  int dsa = ra * 32 + ((c4 ^ (ra & 3)) * 8);

  uint4 r0 = *(const uint4*)(gAh0);
  uint4 r1 = *(const uint4*)(gAh0 + (size_t)64 * C_);
  uint4 r2 = *(const uint4*)(gAl0);
  uint4 r3 = *(const uint4*)(gAl0 + (size_t)64 * C_);
  uint4 r4 = *(const uint4*)(gBh0);
  uint4 r5 = *(const uint4*)(gBl0);

  f32x4 acc[4][2];
  #pragma unroll
  for (int i = 0; i < 4; ++i)
    #pragma unroll
    for (int j = 0; j < 2; ++j) acc[i][j] = (f32x4){0.f, 0.f, 0.f, 0.f};

  int p = 0;
  for (int kk = 0; kk < 12; ++kk) {
    *(uint4*)(&sAh[p][dsa])           = r0;
    *(uint4*)(&sAh[p][dsa + 64 * 32]) = r1;
    *(uint4*)(&sAl[p][dsa])           = r2;
    *(uint4*)(&sAl[p][dsa + 64 * 32]) = r3;
    *(uint4*)(&sBh[p][dsa])           = r4;
    *(uint4*)(&sBl[p][dsa])           = r5;
    __syncthreads();
    if (kk < 11) {
      int ko = (kk + 1) * 32;
      r0 = *(const uint4*)(gAh0 + ko);
      r1 = *(const uint4*)(gAh0 + (size_t)64 * C_ + ko);
      r2 = *(const uint4*)(gAl0 + ko);
      r3 = *(const uint4*)(gAl0 + (size_t)64 * C_ + ko);
      r4 = *(const uint4*)(gBh0 + ko);
      r5 = *(const uint4*)(gBl0 + ko);
    }
    bf16x8 ah[4], al[4], bh8[2], bl8[2];
    #pragma unroll
    for (int i = 0; i < 4; ++i) {
      int row = wr * 64 + i * 16 + lanelo;
      int off = row * 32 + ((g16 ^ (row & 3)) * 8);
      ah[i] = *(const bf16x8*)(&sAh[p][off]);
      al[i] = *(const bf16x8*)(&sAl[p][off]);
    }
    #pragma unroll
    for (int j = 0; j < 2; ++j) {
      int row = wc * 32 + j * 16 + lanelo;
      int off = row * 32 + ((g16 ^ (row & 3)) * 8);
      bh8[j] = *(const bf16x8*)(&sBh[p][off]);
      bl8[j] = *(const bf16x8*)(&sBl[p][off]);
    }
    #pragma unroll
    for (int i = 0; i < 4; ++i)
      #pragma unroll
      for (int j = 0; j < 2; ++j) {
        acc[i][j] = __builtin_amdgcn_mfma_f32_16x16x32_bf16(ah[i], bh8[j], acc[i][j], 0, 0, 0);
        acc[i][j] = __builtin_amdgcn_mfma_f32_16x16x32_bf16(ah[i], bl8[j], acc[i][j], 0, 0, 0);
        acc[i][j] = __builtin_amdgcn_mfma_f32_16x16x32_bf16(al[i], bh8[j], acc[i][j], 0, 0, 0);
      }
    p ^= 1;
  }

  int region = bn / 6;   // 0=Q 1=K 2=V (block-uniform; 6 bn-tiles each)
  #pragma unroll
  for (int i = 0; i < 4; ++i) {
    int mm0 = bm * 128 + wr * 64 + i * 16 + g16 * 4;
    #pragma unroll
    for (int j = 0; j < 2; ++j) {
      int c = bn * 64 + wc * 32 + j * 16 + lanelo;
      int cc = c - region * 384;   // 0..383
      #pragma unroll
      for (int t = 0; t < 4; ++t) {
        int mm = mm0 + t;
        int b = mm >> 10, n = mm & 1023;
        float v = acc[i][j][t];
        if (region == 0) {
          v *= QSCALE;                 // fold log2e: attn uses exp2
          unsigned short h = f2bf(v), lo = f2bf(v - bf2f(h));
          size_t idx = ((size_t)(b * NH_ + (cc >> 5)) * N_ + n) * HD_ + (cc & 31);
          Qh[idx] = h; Ql[idx] = lo;
        } else if (region == 1) {
          unsigned short h = f2bf(v), lo = f2bf(v - bf2f(h));
          size_t idx = ((size_t)(b * NH_ + (cc >> 5)) * N_ + n) * HD_ + (cc & 31);
          Kh[idx] = h; Kl[idx] = lo;
        } else {
          Vf[(size_t)mm * C_ + cc] = v;
        }
      }
    }
  }
}

// ---------------- gemm_proj: 64x64 tile, dbuf LDS, async-stage split --------
__global__ __launch_bounds__(256) void gemm_proj(
    const unsigned short* __restrict__ Ah_g, const unsigned short* __restrict__ Al_g,
    const unsigned short* __restrict__ Bh_g, const unsigned short* __restrict__ Bl_g,
    float* __restrict__ Cm) {
  __shared__ __align__(16) unsigned short sAh[2][64 * 32];
  __shared__ __align__(16) unsigned short sAl[2][64 * 32];
  __shared__ __align__(16) unsigned short sBh[2][64 * 32];
  __shared__ __align__(16) unsigned short sBl[2][64 * 32];
  int tid = threadIdx.x;
  int l = tid & 63, w = tid >> 6;
  int lanelo = l & 15, g16 = l >> 4;
  int wr = w >> 1, wc = w & 1;
  int flat = blockIdx.x;
  int swz = (flat & 7) * 48 + (flat >> 3);   // 384 = 8*48, bijective
  int bm = swz / 6, bn = swz % 6;

  int ra = tid >> 2, c4 = tid & 3;
  const unsigned short* gAh0 = Ah_g + (size_t)(bm * 64 + ra) * C_ + c4 * 8;
  const unsigned short* gAl0 = Al_g + (size_t)(bm * 64 + ra) * C_ + c4 * 8;
  const unsigned short* gBh0 = Bh_g + (size_t)(bn * 64 + ra) * C_ + c4 * 8;
  const unsigned short* gBl0 = Bl_g + (size_t)(bn * 64 + ra) * C_ + c4 * 8;
  int dsa = ra * 32 + ((c4 ^ (ra & 3)) * 8);

  uint4 r0 = *(const uint4*)(gAh0);
  uint4 r1 = *(const uint4*)(gAl0);
  uint4 r2 = *(const uint4*)(gBh0);
  uint4 r3 = *(const uint4*)(gBl0);

  f32x4 acc[2][2];
  #pragma unroll
  for (int i = 0; i < 2; ++i)
    #pragma unroll
    for (int j = 0; j < 2; ++j) acc[i][j] = (f32x4){0.f, 0.f, 0.f, 0.f};

  int p = 0;
  for (int kk = 0; kk < 12; ++kk) {
    *(uint4*)(&sAh[p][dsa]) = r0;
    *(uint4*)(&sAl[p][dsa]) = r1;
    *(uint4*)(&sBh[p][dsa]) = r2;
    *(uint4*)(&sBl[p][dsa]) = r3;
    __syncthreads();
    if (kk < 11) {
      int ko = (kk + 1) * 32;
      r0 = *(const uint4*)(gAh0 + ko);
      r1 = *(const uint4*)(gAl0 + ko);
      r2 = *(const uint4*)(gBh0 + ko);
      r3 = *(const uint4*)(gBl0 + ko);
    }
    bf16x8 ah[2], al[2], bh8[2], bl8[2];
    #pragma unroll
    for (int i = 0; i < 2; ++i) {
      int row = wr * 32 + i * 16 + lanelo;
      int off = row * 32 + ((g16 ^ (row & 3)) * 8);
      ah[i] = *(const bf16x8*)(&sAh[p][off]);
      al[i] = *(const bf16x8*)(&sAl[p][off]);
    }
    #pragma unroll
    for (int j = 0; j < 2; ++j) {
      int row = wc * 32 + j * 16 + lanelo;
      int off = row * 32 + ((g16 ^ (row & 3)) * 8);
      bh8[j] = *(const bf16x8*)(&sBh[p][off]);
      bl8[j] = *(const bf16x8*)(&sBl[p][off]);
    }
    #pragma unroll
    for (int i = 0; i < 2; ++i)
      #pragma unroll
      for (int j = 0; j < 2; ++j) {
        acc[i][j] = __builtin_amdgcn_mfma_f32_16x16x32_bf16(ah[i], bh8[j], acc[i][j], 0, 0, 0);
        acc[i][j] = __builtin_amdgcn_mfma_f32_16x16x32_bf16(ah[i], bl8[j], acc[i][j], 0, 0, 0);
        acc[i][j] = __builtin_amdgcn_mfma_f32_16x16x32_bf16(al[i], bh8[j], acc[i][j], 0, 0, 0);
      }
    p ^= 1;
  }
  #pragma unroll
  for (int i = 0; i < 2; ++i) {
    int mm = bm * 64 + wr * 32 + i * 16 + g16 * 4;
    #pragma unroll
    for (int j = 0; j < 2; ++j) {
      int c = bn * 64 + wc * 32 + j * 16 + lanelo;
      #pragma unroll
      for (int t = 0; t < 4; ++t)
        Cm[(size_t)(mm + t) * C_ + c] = acc[i][j][t];
    }
  }
}

// ---------------- score3: 2 QK^T sweeps, ISSUE-EARLY K staging, exp2 --------
// grid (16 qblk, 48 bh) XCD-swz, 768 blocks; 4 waves x 16 q-rows.
__global__ __launch_bounds__(256) void score3(const unsigned short* __restrict__ Qh,
                                              const unsigned short* __restrict__ Ql,
                                              const unsigned short* __restrict__ Kh,
                                              const unsigned short* __restrict__ Kl,
                                              const int* __restrict__ group,
                                              float* __restrict__ rinv,
                                              float* __restrict__ colpart) {
  __shared__ __align__(16) unsigned short kbufh[4096];   // [128kv][32d] swz
  __shared__ __align__(16) unsigned short kbufl[4096];
  __shared__ float colpart_s[4][1024];
  __shared__ int g_s[1024];
  int tid = threadIdx.x;
  int l = tid & 63, w = tid >> 6;
  int lanelo = l & 15, g16 = l >> 4;
  int flat = blockIdx.y * 16 + blockIdx.x;
  int nf = (flat & 7) * 96 + (flat >> 3);
  int bh = nf >> 4, blk = nf & 15;
  int b = bh / NH_;
  bool samehead = ((bh % NH_) < NH_ / 2);
  int q0 = blk * 64 + w * 16;
  size_t bhb = (size_t)bh * (N_ * HD_);

  *(int4*)&g_s[tid * 4] = *(const int4*)(group + b * N_ + tid * 4);
  bf16x8 aQh = *(const bf16x8*)(Qh + bhb + (size_t)(q0 + lanelo) * HD_ + g16 * 8);
  bf16x8 aQl = *(const bf16x8*)(Ql + bhb + (size_t)(q0 + lanelo) * HD_ + g16 * 8);
  __syncthreads();
  int gq[4];
  #pragma unroll
  for (int t = 0; t < 4; ++t) gq[t] = g_s[q0 + g16 * 4 + t];

  // staging map: rows srow and srow+64; swz offset identical (64%4==0)
  int srow = tid >> 2, sc4 = tid & 3;
  const unsigned short* kh0 = Kh + bhb + (size_t)srow * HD_ + sc4 * 8;
  const unsigned short* kl0 = Kl + bhb + (size_t)srow * HD_ + sc4 * 8;
  int ph0 = srow * 64 + ((sc4 ^ (srow & 3)) << 4);
  const int ROWOFF = 64 * HD_;          // +64 rows in ushorts
  const int PHOFF = 64 * 64;            // +64 rows in bytes (row stride 64B)

  uint4 rh0 = *(const uint4*)(kh0);
  uint4 rh1 = *(const uint4*)(kh0 + ROWOFF);
  uint4 rl0 = *(const uint4*)(kl0);
  uint4 rl1 = *(const uint4*)(kl0 + ROWOFF);

  // sweep 1: row sums
  float s4[4] = {0.f, 0.f, 0.f, 0.f};
  for (int ch = 0; ch < 8; ++ch) {
    if (ch) __syncthreads();
    *(uint4*)((char*)kbufh + ph0)         = rh0;
    *(uint4*)((char*)kbufh + ph0 + PHOFF) = rh1;
    *(uint4*)((char*)kbufl + ph0)         = rl0;
    *(uint4*)((char*)kbufl + ph0 + PHOFF) = rl1;
    __syncthreads();
    if (ch < 7) {
      int ko = (ch + 1) * 128 * HD_;
      rh0 = *(const uint4*)(kh0 + ko);
      rh1 = *(const uint4*)(kh0 + ko + ROWOFF);
      rl0 = *(const uint4*)(kl0 + ko);
      rl1 = *(const uint4*)(kl0 + ko + ROWOFF);
    }
    #pragma unroll
    for (int kt2 = 0; kt2 < 8; ++kt2) {
      int kvl = kt2 * 16 + lanelo;
      int phys = kvl * 64 + ((g16 ^ (kvl & 3)) << 4);
      bf16x8 bh8 = *(const bf16x8*)((char*)kbufh + phys);
      bf16x8 bl8 = *(const bf16x8*)((char*)kbufl + phys);
      f32x4 acc = {0.f, 0.f, 0.f, 0.f};
      acc = __builtin_amdgcn_mfma_f32_16x16x32_bf16(aQh, bh8, acc, 0, 0, 0);
      acc = __builtin_amdgcn_mfma_f32_16x16x32_bf16(aQh, bl8, acc, 0, 0, 0);
      acc = __builtin_amdgcn_mfma_f32_16x16x32_bf16(aQl, bh8, acc, 0, 0, 0);
      #pragma unroll
      for (int t = 0; t < 4; ++t) s4[t] += exp2f(acc[t]);
    }
  }
  // prime sweep-2 ch=0 loads NOW (latency hidden under the reduction)
  rh0 = *(const uint4*)(kh0);
  rh1 = *(const uint4*)(kh0 + ROWOFF);
  rl0 = *(const uint4*)(kl0);
  rl1 = *(const uint4*)(kl0 + ROWOFF);
  float ri[4];
  #pragma unroll
  for (int t = 0; t < 4; ++t) {
    #pragma unroll
    for (int off = 1; off < 16; off <<= 1) s4[t] += __shfl_xor(s4[t], off);
    ri[t] = 1.0f / s4[t];
  }
  if (lanelo == 0) {
    #pragma unroll
    for (int t = 0; t < 4; ++t)
      rinv[(size_t)bh * N_ + q0 + g16 * 4 + t] = ri[t];
  }

  // sweep 2: masked col partial sums (exp2 * ri)
  for (int ch = 0; ch < 8; ++ch) {
    __syncthreads();
    *(uint4*)((char*)kbufh + ph0)         = rh0;
    *(uint4*)((char*)kbufh + ph0 + PHOFF) = rh1;
    *(uint4*)((char*)kbufl + ph0)         = rl0;
    *(uint4*)((char*)kbufl + ph0 + PHOFF) = rl1;
    __syncthreads();
    if (ch < 7) {
      int ko = (ch + 1) * 128 * HD_;
      rh0 = *(const uint4*)(kh0 + ko);
      rh1 = *(const uint4*)(kh0 + ko + ROWOFF);
      rl0 = *(const uint4*)(kl0 + ko);
      rl1 = *(const uint4*)(kl0 + ko + ROWOFF);
    }
    #pragma unroll
    for (int kt2 = 0; kt2 < 8; ++kt2) {
      int kt = ch * 8 + kt2;
      int kvl = kt2 * 16 + lanelo;
      int phys = kvl * 64 + ((g16 ^ (kvl & 3)) << 4);
      bf16x8 bh8 = *(const bf16x8*)((char*)kbufh + phys);
      bf16x8 bl8 = *(const bf16x8*)((char*)kbufl + phys);
      f32x4 acc = {0.f, 0.f, 0.f, 0.f};
      acc = __builtin_amdgcn_mfma_f32_16x16x32_bf16(aQh, bh8, acc, 0, 0, 0);
      acc = __builtin_amdgcn_mfma_f32_16x16x32_bf16(aQh, bl8, acc, 0, 0, 0);
      acc = __builtin_amdgcn_mfma_f32_16x16x32_bf16(aQl, bh8, acc, 0, 0, 0);
      int gcol = g_s[kt * 16 + lanelo];
      float cs = 0.f;
      #pragma unroll
      for (int t = 0; t < 4; ++t) {
        bool keep = ((gcol == gq[t]) == samehead);
        cs += keep ? exp2f(acc[t]) * ri[t] : 0.f;
      }
      cs += __shfl_xor(cs, 16);
      cs += __shfl_xor(cs, 32);
      if (l < 16) colpart_s[w][kt * 16 + l] = cs;
    }
  }
  __syncthreads();
  int c0 = tid * 4;
  float4 p0 = *(float4*)&colpart_s[0][c0];
  float4 p1 = *(float4*)&colpart_s[1][c0];
  float4 p2 = *(float4*)&colpart_s[2][c0];
  float4 p3 = *(float4*)&colpart_s[3][c0];
  float4 rr = {p0.x + p1.x + p2.x + p3.x, p0.y + p1.y + p2.y + p3.y,
               p0.z + p1.z + p2.z + p3.z, p0.w + p1.w + p2.w + p3.w};
  *(float4*)(colpart + ((size_t)(bh * 16 + blk)) * 1024 + c0) = rr;
}

// ---------------- vsplit: colinv + V' = V*colinv (bf16 hi/lo, transposed) ---
__global__ __launch_bounds__(256) void vsplit(const float* __restrict__ colpart,
                                              const float* __restrict__ Vf,
                                              unsigned short* __restrict__ Vth,
                                              unsigned short* __restrict__ Vtl) {
  __shared__ float red[256];
  __shared__ float colinv_s[16];
  __shared__ unsigned short vh_s[32][16];
  __shared__ unsigned short vl_s[32][16];
  int tid = threadIdx.x;
  int flat = blockIdx.y * 64 + blockIdx.x;
  int nf = (flat & 7) * 384 + (flat >> 3);
  int bh = nf >> 6, mt = nf & 63;
  int b = bh / NH_, hd = bh % NH_;

  int p = tid >> 4, m16 = tid & 15;
  red[tid] = colpart[((size_t)(bh * 16 + p)) * 1024 + mt * 16 + m16];
  __syncthreads();
  #pragma unroll
  for (int st = 128; st >= 16; st >>= 1) {
    if (tid < st) red[tid] += red[tid + st];
    __syncthreads();
  }
  if (tid < 16) colinv_s[tid] = 1.0f / (red[tid] + 1e-8f);
  __syncthreads();
  if (tid < 128) {
    int m = tid >> 3, d4 = (tid & 7) * 4;
    float4 v = *(const float4*)(Vf + ((size_t)(b * N_ + mt * 16 + m)) * C_ +
                                hd * HD_ + d4);
    float ci = colinv_s[m];
    float va[4] = {v.x * ci, v.y * ci, v.z * ci, v.w * ci};
    #pragma unroll
    for (int i = 0; i < 4; ++i) {
      unsigned short h = f2bf(va[i]);
      vh_s[d4 + i][m] = h;
      vl_s[d4 + i][m] = f2bf(va[i] - bf2f(h));
    }
  }
  __syncthreads();
  if (tid < 64) {
    int d = tid >> 1, m8 = (tid & 1) * 8;
    uint4 h = *(uint4*)&vh_s[d][m8];
    *(uint4*)(Vth + ((size_t)bh * HD_ + d) * N_ + mt * 16 + m8) = h;
  } else if (tid < 128) {
    int t2 = tid - 64;
    int d = t2 >> 1, m8 = (t2 & 1) * 8;
    uint4 lo = *(uint4*)&vl_s[d][m8];
    *(uint4*)(Vtl + ((size_t)bh * HD_ + d) * N_ + mt * 16 + m8) = lo;
  }
}

// ---------------- pv3: recompute S, PV MFMA, ISSUE-EARLY K+V staging --------
// grid (16 qblk, 48 bh) XCD-swz; 4 waves x 16 q-rows.
__global__ __launch_bounds__(256) void pv3(const unsigned short* __restrict__ Qh,
                                           const unsigned short* __restrict__ Ql,
                                           const unsigned short* __restrict__ Kh,
                                           const unsigned short* __restrict__ Kl,
                                           const unsigned short* __restrict__ Vth,
                                           const unsigned short* __restrict__ Vtl,
                                           const int* __restrict__ group,
                                           const float* __restrict__ rinv,
                                           unsigned short* __restrict__ aoh,
                                           unsigned short* __restrict__ aol) {
  __shared__ __align__(16) unsigned short kbufh[4096];   // [128kv][32d] swz
  __shared__ __align__(16) unsigned short kbufl[4096];
  __shared__ __align__(16) unsigned short vbufh[4096];   // [32d][128kv] swz
  __shared__ __align__(16) unsigned short vbufl[4096];
  __shared__ __align__(16) float bounce[4][512];         // [wave][16q][32kv] swz
  __shared__ int g_s[1024];
  int tid = threadIdx.x;
  int l = tid & 63, w = tid >> 6;
  int lanelo = l & 15, g16 = l >> 4;
  int flat = blockIdx.y * 16 + blockIdx.x;
  int nf = (flat & 7) * 96 + (flat >> 3);
  int bh = nf >> 4, blk = nf & 15;
  int b = bh / NH_, hd = bh % NH_;
  bool samehead = (hd < NH_ / 2);
  int q0 = blk * 64 + w * 16;
  size_t bhb = (size_t)bh * (N_ * HD_);

  *(int4*)&g_s[tid * 4] = *(const int4*)(group + b * N_ + tid * 4);
  bf16x8 aQh = *(const bf16x8*)(Qh + bhb + (size_t)(q0 + lanelo) * HD_ + g16 * 8);
  bf16x8 aQl = *(const bf16x8*)(Ql + bhb + (size_t)(q0 + lanelo) * HD_ + g16 * 8);
  float ri[4];
  #pragma unroll
  for (int t = 0; t < 4; ++t)
    ri[t] = rinv[(size_t)bh * N_ + q0 + g16 * 4 + t];
  __syncthreads();
  int gq[4];
  #pragma unroll
  for (int t = 0; t < 4; ++t) gq[t] = g_s[q0 + g16 * 4 + t];

  // K staging map (rows srow, srow+64)
  int srow = tid >> 2, sc4 = tid & 3;
  const unsigned short* kh0 = Kh + bhb + (size_t)srow * HD_ + sc4 * 8;
  const unsigned short* kl0 = Kl + bhb + (size_t)srow * HD_ + sc4 * 8;
  int kp0 = srow * 64 + ((sc4 ^ (srow & 3)) << 4);
  const int KROWOFF = 64 * HD_;
  const int KPHOFF = 64 * 64;
  // V staging map (d = vd0, vd0+16)
  int vd0 = tid >> 4, vc0 = tid & 15;
  const unsigned short* vh0 = Vth + bhb + (size_t)vd0 * N_ + vc0 * 8;
  const unsigned short* vl0 = Vtl + bhb + (size_t)vd0 * N_ + vc0 * 8;
  int vp0 = vd0 * 128 + ((vc0 ^ (vd0 & 15)) * 8);
  const int VROWOFF = 16 * N_;
  const int VPOFF = 16 * 128;

  uint4 krh0 = *(const uint4*)(kh0);
  uint4 krh1 = *(const uint4*)(kh0 + KROWOFF);
  uint4 krl0 = *(const uint4*)(kl0);
  uint4 krl1 = *(const uint4*)(kl0 + KROWOFF);
  uint4 vrh0 = *(const uint4*)(vh0);
  uint4 vrh1 = *(const uint4*)(vh0 + VROWOFF);
  uint4 vrl0 = *(const uint4*)(vl0);
  uint4 vrl1 = *(const uint4*)(vl0 + VROWOFF);

  f32x4 o0 = {0.f, 0.f, 0.f, 0.f};   // rows x d[0..15]
  f32x4 o1 = {0.f, 0.f, 0.f, 0.f};   // rows x d[16..31]

  for (int ch = 0; ch < 8; ++ch) {
    if (ch) __syncthreads();
    *(uint4*)((char*)kbufh + kp0)          = krh0;
    *(uint4*)((char*)kbufh + kp0 + KPHOFF) = krh1;
    *(uint4*)((char*)kbufl + kp0)          = krl0;
    *(uint4*)((char*)kbufl + kp0 + KPHOFF) = krl1;
    *(uint4*)(vbufh + vp0)         = vrh0;
    *(uint4*)(vbufh + vp0 + VPOFF) = vrh1;
    *(uint4*)(vbufl + vp0)         = vrl0;
    *(uint4*)(vbufl + vp0 + VPOFF) = vrl1;
    __syncthreads();
    if (ch < 7) {
      int kko = (ch + 1) * 128 * HD_;
      int vko = (ch + 1) * 128;
      krh0 = *(const uint4*)(kh0 + kko);
      krh1 = *(const uint4*)(kh0 + kko + KROWOFF);
      krl0 = *(const uint4*)(kl0 + kko);
      krl1 = *(const uint4*)(kl0 + kko + KROWOFF);
      vrh0 = *(const uint4*)(vh0 + vko);
      vrh1 = *(const uint4*)(vh0 + vko + VROWOFF);
      vrl0 = *(const uint4*)(vl0 + vko);
      vrl1 = *(const uint4*)(vl0 + vko + VROWOFF);
    }

    #pragma unroll
    for (int pair = 0; pair < 4; ++pair) {     // 32 kv per pair
      f32x4 sa[2];
      #pragma unroll
      for (int half = 0; half < 2; ++half) {
        int kvl = pair * 32 + half * 16 + lanelo;
        int phys = kvl * 64 + ((g16 ^ (kvl & 3)) << 4);
        bf16x8 bh8 = *(const bf16x8*)((char*)kbufh + phys);
        bf16x8 bl8 = *(const bf16x8*)((char*)kbufl + phys);
        f32x4 acc = {0.f, 0.f, 0.f, 0.f};
        acc = __builtin_amdgcn_mfma_f32_16x16x32_bf16(aQh, bh8, acc, 0, 0, 0);
        acc = __builtin_amdgcn_mfma_f32_16x16x32_bf16(aQh, bl8, acc, 0, 0, 0);
        acc = __builtin_amdgcn_mfma_f32_16x16x32_bf16(aQl, bh8, acc, 0, 0, 0);
        sa[half] = acc;
      }
      #pragma unroll
      for (int half = 0; half < 2; ++half) {
        int kvloc = pair * 32 + half * 16 + lanelo;
        int gcol = g_s[ch * 128 + kvloc];
        int kv = half * 16 + lanelo;
        int chunk = kv >> 2;
        #pragma unroll
        for (int t = 0; t < 4; ++t) {
          bool keep = ((gcol == gq[t]) == samehead);
          float p = keep ? exp2f(sa[half][t]) : 0.f;
          int q = g16 * 4 + t;
          bounce[w][q * 32 + ((chunk ^ (q & 7)) << 2) + (kv & 3)] = p;
        }
      }
      float pf[8];
      int q2 = lanelo;
      int c0i = (2 * g16) ^ (q2 & 7), c1i = (2 * g16 + 1) ^ (q2 & 7);
      *(float4*)&pf[0] = *(float4*)&bounce[w][q2 * 32 + c0i * 4];
      *(float4*)&pf[4] = *(float4*)&bounce[w][q2 * 32 + c1i * 4];
      bf16x8 pa;
      #pragma unroll
      for (int j = 0; j < 8; ++j) pa[j] = (short)f2bf(pf[j]);
      int vchunk = pair * 4 + g16;
      int d0 = lanelo, d1 = 16 + lanelo;
      bf16x8 v0h = *(const bf16x8*)(vbufh + d0 * 128 + ((vchunk ^ (d0 & 15)) << 3));
      bf16x8 v0l = *(const bf16x8*)(vbufl + d0 * 128 + ((vchunk ^ (d0 & 15)) << 3));
      bf16x8 v1h = *(const bf16x8*)(vbufh + d1 * 128 + ((vchunk ^ (d1 & 15)) << 3));
      bf16x8 v1l = *(const bf16x8*)(vbufl + d1 * 128 + ((vchunk ^ (d1 & 15)) << 3));
      o0 = __builtin_amdgcn_mfma_f32_16x16x32_bf16(pa, v0h, o0, 0, 0, 0);
      o0 = __builtin_amdgcn_mfma_f32_16x16x32_bf16(pa, v0l, o0, 0, 0, 0);
      o1 = __builtin_amdgcn_mfma_f32_16x16x32_bf16(pa, v1h, o1, 0, 0, 0);
      o1 = __builtin_amdgcn_mfma_f32_16x16x32_bf16(pa, v1l, o1, 0, 0, 0);
    }
  }
  #pragma unroll
  for (int t = 0; t < 4; ++t) {
    size_t row = (size_t)(b * N_ + q0 + g16 * 4 + t) * C_ + hd * HD_;
    float v0 = o0[t] * ri[t], v1 = o1[t] * ri[t];
    unsigned short h;
    h = f2bf(v0); aoh[row + lanelo]      = h; aol[row + lanelo]      = f2bf(v0 - bf2f(h));
    h = f2bf(v1); aoh[row + 16 + lanelo] = h; aol[row + 16 + lanelo] = f2bf(v1 - bf2f(h));
  }
}

// ---------------- launch ----------------------------------------------------
extern "C" void kernel_launch(void* const* d_in, const int* in_sizes, int n_in,
                              void* d_out, int out_size, void* d_ws, size_t ws_size,
                              hipStream_t stream) {
  const float* x     = (const float*)d_in[0];
  const float* Wqkv  = (const float*)d_in[1];
  const float* Wproj = (const float*)d_in[2];
  const float* Wgp   = (const float*)d_in[3];
  float* out = (float*)d_out;

  char* base = (char*)d_ws;
  size_t off = 0;
  auto alloc = [&](size_t bytes) {
    void* p = base + off;
    off += (bytes + 255) & ~(size_t)255;
    return p;
  };
  float*  Vf      = (float*)alloc(4096ull * C_ * 4);            // 6.3 MB
  float*  rinv    = (float*)alloc((size_t)BH_ * N_ * 4);
  float*  colpart = (float*)alloc((size_t)BH_ * 16 * N_ * 4);   // 3 MB
  double* Mgp     = (double*)alloc((size_t)GP_ * C_ * 8);
  int*    group   = (int*)alloc(4096ull * 4);
  unsigned short* xh  = (unsigned short*)alloc(4096ull * C_ * 2);
  unsigned short* xl  = (unsigned short*)alloc(4096ull * C_ * 2);
  unsigned short* Wqh = (unsigned short*)alloc((size_t)H3_ * C_ * 2);
  unsigned short* Wql = (unsigned short*)alloc((size_t)H3_ * C_ * 2);
  unsigned short* Wph = (unsigned short*)alloc((size_t)C_ * C_ * 2);
  unsigned short* Wpl = (unsigned short*)alloc((size_t)C_ * C_ * 2);
  unsigned short* aoh = (unsigned short*)alloc(4096ull * C_ * 2);
  unsigned short* aol = (unsigned short*)alloc(4096ull * C_ * 2);
  const size_t BSZ = (size_t)BH_ * N_ * HD_;
  unsigned short* Qh  = (unsigned short*)alloc(BSZ * 2);
  unsigned short* Ql  = (unsigned short*)alloc(BSZ * 2);
  unsigned short* Kh  = (unsigned short*)alloc(BSZ * 2);
  unsigned short* Kl  = (unsigned short*)alloc(BSZ * 2);
  unsigned short* Vth = (unsigned short*)alloc(BSZ * 2);
  unsigned short* Vtl = (unsigned short*)alloc(BSZ * 2);

  conv3<<<dim3(2112), 256, 0, stream>>>(x, Wqkv, Wproj, xh, xl, Wqh, Wql, Wph, Wpl);
  wgp_fuse<<<dim3(30), 256, 0, stream>>>(Wqkv, Wgp, Mgp);
  group_assign2<<<dim3(256), 320, 0, stream>>>(x, Mgp, group);
  gemm_qkv<<<dim3(576), 256, 0, stream>>>(xh, xl, Wqh, Wql,
                                          Qh, Ql, Kh, Kl, Vf);
  score3<<<dim3(16, BH_), 256, 0, stream>>>(Qh, Ql, Kh, Kl, group, rinv, colpart);
  vsplit<<<dim3(64, BH_), 256, 0, stream>>>(colpart, Vf, Vth, Vtl);
  pv3<<<dim3(16, BH_), 256, 0, stream>>>(Qh, Ql, Kh, Kl, Vth, Vtl, group,
                                         rinv, aoh, aol);
  gemm_proj<<<dim3(384), 256, 0, stream>>>(aoh, aol, Wph, Wpl, out);
}

// Round 19
// 165.658 us; speedup vs baseline: 1.0605x; 1.0605x over previous
//
#include <hip/hip_runtime.h>
#include <hip/hip_bf16.h>

// HardgroupAttention: B=4, N=1024, C=384, heads=12, hd=32, GP=20.
// R11 best-known configuration (167 us), restored.
// conv3 -> wgp_fuse + group argmax (fp64 exact, vectorized) -> gemm_qkv
// (128x64 dbuf, async-stage split) -> score3 (2 QK^T MFMA sweeps) ->
// vsplit (colinv + V'=V*colinv bf16 hi/lo transposed) -> pv3 (recompute S,
// PV MFMA, *rinv) -> gemm_proj (64x64 dbuf).

#define B_    4
#define N_    1024
#define C_    384
#define H3_   1152
#define NH_   12
#define HD_   32
#define GP_   20
#define BH_   48
#define SCALE 0.17677669529663687f

typedef __attribute__((ext_vector_type(8))) short bf16x8;
typedef __attribute__((ext_vector_type(4))) float f32x4;

static __device__ __forceinline__ unsigned short f2bf(float x) {
  union { float f; unsigned u; } v; v.f = x;
  unsigned r = v.u + 0x7fff + ((v.u >> 16) & 1);   // RNE
  return (unsigned short)(r >> 16);
}
static __device__ __forceinline__ float bf2f(unsigned short h) {
  union { unsigned u; float f; } v; v.u = ((unsigned)h) << 16;
  return v.f;
}

// ---------------- conv3: split x / Wqkv / Wproj into bf16 hi/lo -------------
__global__ __launch_bounds__(256) void conv3(const float* __restrict__ x,
                                             const float* __restrict__ wq,
                                             const float* __restrict__ wp,
                                             unsigned short* __restrict__ xh,
                                             unsigned short* __restrict__ xl,
                                             unsigned short* __restrict__ wqh,
                                             unsigned short* __restrict__ wql,
                                             unsigned short* __restrict__ wph,
                                             unsigned short* __restrict__ wpl) {
  const int NX = (4096 * C_) / 4, NQ = (H3_ * C_) / 4, NP = (C_ * C_) / 4;
  int idx = blockIdx.x * 256 + threadIdx.x;
  const float* src; unsigned short *dh, *dl; int o;
  if (idx < NX)            { src = x;  dh = xh;  dl = xl;  o = idx; }
  else if (idx < NX + NQ)  { src = wq; dh = wqh; dl = wql; o = idx - NX; }
  else if (idx < NX + NQ + NP) { src = wp; dh = wph; dl = wpl; o = idx - NX - NQ; }
  else return;
  float4 v = *(const float4*)(src + (size_t)o * 4);
  float a[4] = {v.x, v.y, v.z, v.w};
  unsigned short h[4], lo[4];
  #pragma unroll
  for (int i = 0; i < 4; ++i) { h[i] = f2bf(a[i]); lo[i] = f2bf(a[i] - bf2f(h[i])); }
  uint2 ph = {(unsigned)h[0]  | ((unsigned)h[1]  << 16),
              (unsigned)h[2]  | ((unsigned)h[3]  << 16)};
  uint2 pl = {(unsigned)lo[0] | ((unsigned)lo[1] << 16),
              (unsigned)lo[2] | ((unsigned)lo[3] << 16)};
  *(uint2*)(dh + (size_t)o * 4) = ph;
  *(uint2*)(dl + (size_t)o * 4) = pl;
}

// ---------------- M[g][c] = sum_j Wgp[g][j] * Wqkv[j][c]  (fp64) ------------
__global__ __launch_bounds__(256) void wgp_fuse(const float* __restrict__ Wqkv,
                                                const float* __restrict__ Wgp,
                                                double* __restrict__ M) {
  int idx = blockIdx.x * 256 + threadIdx.x;
  if (idx >= GP_ * C_) return;
  int g = idx / C_, c = idx % C_;
  double acc = 0.0;
  for (int j = 0; j < C_; ++j)
    acc += (double)Wgp[g * C_ + j] * (double)Wqkv[(size_t)j * C_ + c];
  M[idx] = acc;
}

// ---------------- group argmax from exact x (fp64, vectorized loads) --------
__global__ __launch_bounds__(320) void group_assign2(const float* __restrict__ x,
                                                     const double* __restrict__ M,
                                                     int* __restrict__ group) {
  __shared__ double sc[16][GP_];
  int tid = threadIdx.x;
  int r = tid / GP_, g = tid % GP_;
  int n = blockIdx.x * 16 + r;
  const float* row = x + (size_t)n * C_;
  const double* w = M + (size_t)g * C_;
  double acc = 0.0;
  #pragma unroll 4
  for (int c = 0; c < C_; c += 4) {
    float4 xv = *(const float4*)(row + c);
    double2 w0 = *(const double2*)(w + c);
    double2 w1 = *(const double2*)(w + c + 2);
    acc += (double)xv.x * w0.x + (double)xv.y * w0.y +
           (double)xv.z * w1.x + (double)xv.w * w1.y;
  }
  sc[r][g] = acc;
  __syncthreads();
  if (g == 0) {
    int best = 0; double bv = sc[r][0];
    #pragma unroll
    for (int j = 1; j < GP_; ++j)
      if (sc[r][j] > bv) { bv = sc[r][j]; best = j; }
    group[n] = best;
  }
}

// ---------------- gemm_qkv: 128x64 tile, dbuf LDS, async-stage split --------
__global__ __launch_bounds__(256) void gemm_qkv(
    const unsigned short* __restrict__ Ah_g, const unsigned short* __restrict__ Al_g,
    const unsigned short* __restrict__ Bh_g, const unsigned short* __restrict__ Bl_g,
    unsigned short* __restrict__ Qh, unsigned short* __restrict__ Ql,
    unsigned short* __restrict__ Kh, unsigned short* __restrict__ Kl,
    float* __restrict__ Vf) {
  __shared__ __align__(16) unsigned short sAh[2][128 * 32];
  __shared__ __align__(16) unsigned short sAl[2][128 * 32];
  __shared__ __align__(16) unsigned short sBh[2][64 * 32];
  __shared__ __align__(16) unsigned short sBl[2][64 * 32];
  int tid = threadIdx.x;
  int l = tid & 63, w = tid >> 6;
  int lanelo = l & 15, g16 = l >> 4;
  int wr = w >> 1, wc = w & 1;
  int flat = blockIdx.x;
  int swz = (flat & 7) * 72 + (flat >> 3);   // 576 = 8*72, bijective
  int bm = swz / 18, bn = swz % 18;

  int ra = tid >> 2, c4 = tid & 3;
  const unsigned short* gAh0 = Ah_g + (size_t)(bm * 128 + ra) * C_ + c4 * 8;
  const unsigned short* gAl0 = Al_g + (size_t)(bm * 128 + ra) * C_ + c4 * 8;
  const unsigned short* gBh0 = Bh_g + (size_t)(bn * 64 + ra) * C_ + c4 * 8;
  const unsigned short* gBl0 = Bl_g + (size_t)(bn * 64 + ra) * C_ + c4 * 8;
  int dsa = ra * 32 + ((c4 ^ (ra & 3)) * 8);

  uint4 r0 = *(const uint4*)(gAh0);
  uint4 r1 = *(const uint4*)(gAh0 + (size_t)64 * C_);
  uint4 r2 = *(const uint4*)(gAl0);
  uint4 r3 = *(const uint4*)(gAl0 + (size_t)64 * C_);
  uint4 r4 = *(const uint4*)(gBh0);
  uint4 r5 = *(const uint4*)(gBl0);

  f32x4 acc[4][2];
  #pragma unroll
  for (int i = 0; i < 4; ++i)
    #pragma unroll
    for (int j = 0; j < 2; ++j) acc[i][j] = (f32x4){0.f, 0.f, 0.f, 0.f};

  int p = 0;
  for (int kk = 0; kk < 12; ++kk) {
    *(uint4*)(&sAh[p][dsa])           = r0;
    *(uint4*)(&sAh[p][dsa + 64 * 32]) = r1;
    *(uint4*)(&sAl[p][dsa])           = r2;
    *(uint4*)(&sAl[p][dsa + 64 * 32]) = r3;
    *(uint4*)(&sBh[p][dsa])           = r4;
    *(uint4*)(&sBl[p][dsa])           = r5;
    __syncthreads();
    if (kk < 11) {
      int ko = (kk + 1) * 32;
      r0 = *(const uint4*)(gAh0 + ko);
      r1 = *(const uint4*)(gAh0 + (size_t)64 * C_ + ko);
      r2 = *(const uint4*)(gAl0 + ko);
      r3 = *(const uint4*)(gAl0 + (size_t)64 * C_ + ko);
      r4 = *(const uint4*)(gBh0 + ko);
      r5 = *(const uint4*)(gBl0 + ko);
    }
    bf16x8 ah[4], al[4], bh8[2], bl8[2];
    #pragma unroll
    for (int i = 0; i < 4; ++i) {
      int row = wr * 64 + i * 16 + lanelo;
      int off = row * 32 + ((g16 ^ (row & 3)) * 8);
      ah[i] = *(const bf16x8*)(&sAh[p][off]);
      al[i] = *(const bf16x8*)(&sAl[p][off]);
    }
    #pragma unroll
    for (int j = 0; j < 2; ++j) {
      int row = wc * 32 + j * 16 + lanelo;
      int off = row * 32 + ((g16 ^ (row & 3)) * 8);
      bh8[j] = *(const bf16x8*)(&sBh[p][off]);
      bl8[j] = *(const bf16x8*)(&sBl[p][off]);
    }
    #pragma unroll
    for (int i = 0; i < 4; ++i)
      #pragma unroll
      for (int j = 0; j < 2; ++j) {
        acc[i][j] = __builtin_amdgcn_mfma_f32_16x16x32_bf16(ah[i], bh8[j], acc[i][j], 0, 0, 0);
        acc[i][j] = __builtin_amdgcn_mfma_f32_16x16x32_bf16(ah[i], bl8[j], acc[i][j], 0, 0, 0);
        acc[i][j] = __builtin_amdgcn_mfma_f32_16x16x32_bf16(al[i], bh8[j], acc[i][j], 0, 0, 0);
      }
    p ^= 1;
  }

  int region = bn / 6;   // 0=Q 1=K 2=V (block-uniform; 6 bn-tiles each)
  #pragma unroll
  for (int i = 0; i < 4; ++i) {
    int mm0 = bm * 128 + wr * 64 + i * 16 + g16 * 4;
    #pragma unroll
    for (int j = 0; j < 2; ++j) {
      int c = bn * 64 + wc * 32 + j * 16 + lanelo;
      int cc = c - region * 384;   // 0..383
      #pragma unroll
      for (int t = 0; t < 4; ++t) {
        int mm = mm0 + t;
        int b = mm >> 10, n = mm & 1023;
        float v = acc[i][j][t];
        if (region == 0) {
          v *= SCALE;
          unsigned short h = f2bf(v), lo = f2bf(v - bf2f(h));
          size_t idx = ((size_t)(b * NH_ + (cc >> 5)) * N_ + n) * HD_ + (cc & 31);
          Qh[idx] = h; Ql[idx] = lo;
        } else if (region == 1) {
          unsigned short h = f2bf(v), lo = f2bf(v - bf2f(h));
          size_t idx = ((size_t)(b * NH_ + (cc >> 5)) * N_ + n) * HD_ + (cc & 31);
          Kh[idx] = h; Kl[idx] = lo;
        } else {
          Vf[(size_t)mm * C_ + cc] = v;
        }
      }
    }
  }
}

// ---------------- gemm_proj: 64x64 tile, dbuf LDS, async-stage split --------
__global__ __launch_bounds__(256) void gemm_proj(
    const unsigned short* __restrict__ Ah_g, const unsigned short* __restrict__ Al_g,
    const unsigned short* __restrict__ Bh_g, const unsigned short* __restrict__ Bl_g,
    float* __restrict__ Cm) {
  __shared__ __align__(16) unsigned short sAh[2][64 * 32];
  __shared__ __align__(16) unsigned short sAl[2][64 * 32];
  __shared__ __align__(16) unsigned short sBh[2][64 * 32];
  __shared__ __align__(16) unsigned short sBl[2][64 * 32];
  int tid = threadIdx.x;
  int l = tid & 63, w = tid >> 6;
  int lanelo = l & 15, g16 = l >> 4;
  int wr = w >> 1, wc = w & 1;
  int flat = blockIdx.x;
  int swz = (flat & 7) * 48 + (flat >> 3);   // 384 = 8*48, bijective
  int bm = swz / 6, bn = swz % 6;

  int ra = tid >> 2, c4 = tid & 3;
  const unsigned short* gAh0 = Ah_g + (size_t)(bm * 64 + ra) * C_ + c4 * 8;
  const unsigned short* gAl0 = Al_g + (size_t)(bm * 64 + ra) * C_ + c4 * 8;
  const unsigned short* gBh0 = Bh_g + (size_t)(bn * 64 + ra) * C_ + c4 * 8;
  const unsigned short* gBl0 = Bl_g + (size_t)(bn * 64 + ra) * C_ + c4 * 8;
  int dsa = ra * 32 + ((c4 ^ (ra & 3)) * 8);

  uint4 r0 = *(const uint4*)(gAh0);
  uint4 r1 = *(const uint4*)(gAl0);
  uint4 r2 = *(const uint4*)(gBh0);
  uint4 r3 = *(const uint4*)(gBl0);

  f32x4 acc[2][2];
  #pragma unroll
  for (int i = 0; i < 2; ++i)
    #pragma unroll
    for (int j = 0; j < 2; ++j) acc[i][j] = (f32x4){0.f, 0.f, 0.f, 0.f};

  int p = 0;
  for (int kk = 0; kk < 12; ++kk) {
    *(uint4*)(&sAh[p][dsa]) = r0;
    *(uint4*)(&sAl[p][dsa]) = r1;
    *(uint4*)(&sBh[p][dsa]) = r2;
    *(uint4*)(&sBl[p][dsa]) = r3;
    __syncthreads();
    if (kk < 11) {
      int ko = (kk + 1) * 32;
      r0 = *(const uint4*)(gAh0 + ko);
      r1 = *(const uint4*)(gAl0 + ko);
      r2 = *(const uint4*)(gBh0 + ko);
      r3 = *(const uint4*)(gBl0 + ko);
    }
    bf16x8 ah[2], al[2], bh8[2], bl8[2];
    #pragma unroll
    for (int i = 0; i < 2; ++i) {
      int row = wr * 32 + i * 16 + lanelo;
      int off = row * 32 + ((g16 ^ (row & 3)) * 8);
      ah[i] = *(const bf16x8*)(&sAh[p][off]);
      al[i] = *(const bf16x8*)(&sAl[p][off]);
    }
    #pragma unroll
    for (int j = 0; j < 2; ++j) {
      int row = wc * 32 + j * 16 + lanelo;
      int off = row * 32 + ((g16 ^ (row & 3)) * 8);
      bh8[j] = *(const bf16x8*)(&sBh[p][off]);
      bl8[j] = *(const bf16x8*)(&sBl[p][off]);
    }
    #pragma unroll
    for (int i = 0; i < 2; ++i)
      #pragma unroll
      for (int j = 0; j < 2; ++j) {
        acc[i][j] = __builtin_amdgcn_mfma_f32_16x16x32_bf16(ah[i], bh8[j], acc[i][j], 0, 0, 0);
        acc[i][j] = __builtin_amdgcn_mfma_f32_16x16x32_bf16(ah[i], bl8[j], acc[i][j], 0, 0, 0);
        acc[i][j] = __builtin_amdgcn_mfma_f32_16x16x32_bf16(al[i], bh8[j], acc[i][j], 0, 0, 0);
      }
    p ^= 1;
  }
  #pragma unroll
  for (int i = 0; i < 2; ++i) {
    int mm = bm * 64 + wr * 32 + i * 16 + g16 * 4;
    #pragma unroll
    for (int j = 0; j < 2; ++j) {
      int c = bn * 64 + wc * 32 + j * 16 + lanelo;
      #pragma unroll
      for (int t = 0; t < 4; ++t)
        Cm[(size_t)(mm + t) * C_ + c] = acc[i][j][t];
    }
  }
}

// ---------------- score3: 2 QK^T sweeps -> rinv + masked col partials -------
__global__ __launch_bounds__(256) void score3(const unsigned short* __restrict__ Qh,
                                              const unsigned short* __restrict__ Ql,
                                              const unsigned short* __restrict__ Kh,
                                              const unsigned short* __restrict__ Kl,
                                              const int* __restrict__ group,
                                              float* __restrict__ rinv,
                                              float* __restrict__ colpart) {
  __shared__ __align__(16) unsigned short kbufh[4096];   // [128kv][32d] swz
  __shared__ __align__(16) unsigned short kbufl[4096];
  __shared__ float colpart_s[4][1024];
  __shared__ int g_s[1024];
  int tid = threadIdx.x;
  int l = tid & 63, w = tid >> 6;
  int lanelo = l & 15, g16 = l >> 4;
  int flat = blockIdx.y * 16 + blockIdx.x;
  int nf = (flat & 7) * 96 + (flat >> 3);
  int bh = nf >> 4, blk = nf & 15;
  int b = bh / NH_;
  bool samehead = ((bh % NH_) < NH_ / 2);
  int q0 = blk * 64 + w * 16;
  size_t bhb = (size_t)bh * (N_ * HD_);

  *(int4*)&g_s[tid * 4] = *(const int4*)(group + b * N_ + tid * 4);
  bf16x8 aQh = *(const bf16x8*)(Qh + bhb + (size_t)(q0 + lanelo) * HD_ + g16 * 8);
  bf16x8 aQl = *(const bf16x8*)(Ql + bhb + (size_t)(q0 + lanelo) * HD_ + g16 * 8);
  __syncthreads();
  int gq[4];
  #pragma unroll
  for (int t = 0; t < 4; ++t) gq[t] = g_s[q0 + g16 * 4 + t];

  // sweep 1: row sums
  float s4[4] = {0.f, 0.f, 0.f, 0.f};
  for (int ch = 0; ch < 8; ++ch) {
    __syncthreads();
    #pragma unroll
    for (int t2 = 0; t2 < 2; ++t2) {
      int f2 = t2 * 256 + tid;
      int row = f2 >> 2, c4 = f2 & 3;
      uint4 vh = *(const uint4*)(Kh + bhb + (size_t)(ch * 128 + row) * HD_ + c4 * 8);
      uint4 vl = *(const uint4*)(Kl + bhb + (size_t)(ch * 128 + row) * HD_ + c4 * 8);
      int phys = row * 64 + ((c4 ^ (row & 3)) << 4);
      *(uint4*)((char*)kbufh + phys) = vh;
      *(uint4*)((char*)kbufl + phys) = vl;
    }
    __syncthreads();
    #pragma unroll
    for (int kt2 = 0; kt2 < 8; ++kt2) {
      int kvl = kt2 * 16 + lanelo;
      int phys = kvl * 64 + ((g16 ^ (kvl & 3)) << 4);
      bf16x8 bh8 = *(const bf16x8*)((char*)kbufh + phys);
      bf16x8 bl8 = *(const bf16x8*)((char*)kbufl + phys);
      f32x4 acc = {0.f, 0.f, 0.f, 0.f};
      acc = __builtin_amdgcn_mfma_f32_16x16x32_bf16(aQh, bh8, acc, 0, 0, 0);
      acc = __builtin_amdgcn_mfma_f32_16x16x32_bf16(aQh, bl8, acc, 0, 0, 0);
      acc = __builtin_amdgcn_mfma_f32_16x16x32_bf16(aQl, bh8, acc, 0, 0, 0);
      #pragma unroll
      for (int t = 0; t < 4; ++t) s4[t] += __expf(acc[t]);
    }
  }
  float ri[4];
  #pragma unroll
  for (int t = 0; t < 4; ++t) {
    #pragma unroll
    for (int off = 1; off < 16; off <<= 1) s4[t] += __shfl_xor(s4[t], off);
    ri[t] = 1.0f / s4[t];
  }
  if (lanelo == 0) {
    #pragma unroll
    for (int t = 0; t < 4; ++t)
      rinv[(size_t)bh * N_ + q0 + g16 * 4 + t] = ri[t];
  }

  // sweep 2: masked col partial sums (exp * ri)
  for (int ch = 0; ch < 8; ++ch) {
    __syncthreads();
    #pragma unroll
    for (int t2 = 0; t2 < 2; ++t2) {
      int f2 = t2 * 256 + tid;
      int row = f2 >> 2, c4 = f2 & 3;
      uint4 vh = *(const uint4*)(Kh + bhb + (size_t)(ch * 128 + row) * HD_ + c4 * 8);
      uint4 vl = *(const uint4*)(Kl + bhb + (size_t)(ch * 128 + row) * HD_ + c4 * 8);
      int phys = row * 64 + ((c4 ^ (row & 3)) << 4);
      *(uint4*)((char*)kbufh + phys) = vh;
      *(uint4*)((char*)kbufl + phys) = vl;
    }
    __syncthreads();
    #pragma unroll
    for (int kt2 = 0; kt2 < 8; ++kt2) {
      int kt = ch * 8 + kt2;
      int kvl = kt2 * 16 + lanelo;
      int phys = kvl * 64 + ((g16 ^ (kvl & 3)) << 4);
      bf16x8 bh8 = *(const bf16x8*)((char*)kbufh + phys);
      bf16x8 bl8 = *(const bf16x8*)((char*)kbufl + phys);
      f32x4 acc = {0.f, 0.f, 0.f, 0.f};
      acc = __builtin_amdgcn_mfma_f32_16x16x32_bf16(aQh, bh8, acc, 0, 0, 0);
      acc = __builtin_amdgcn_mfma_f32_16x16x32_bf16(aQh, bl8, acc, 0, 0, 0);
      acc = __builtin_amdgcn_mfma_f32_16x16x32_bf16(aQl, bh8, acc, 0, 0, 0);
      int gcol = g_s[kt * 16 + lanelo];
      float cs = 0.f;
      #pragma unroll
      for (int t = 0; t < 4; ++t) {
        bool keep = ((gcol == gq[t]) == samehead);
        cs += keep ? __expf(acc[t]) * ri[t] : 0.f;
      }
      cs += __shfl_xor(cs, 16);
      cs += __shfl_xor(cs, 32);
      if (l < 16) colpart_s[w][kt * 16 + l] = cs;
    }
  }
  __syncthreads();
  int c0 = tid * 4;
  float4 p0 = *(float4*)&colpart_s[0][c0];
  float4 p1 = *(float4*)&colpart_s[1][c0];
  float4 p2 = *(float4*)&colpart_s[2][c0];
  float4 p3 = *(float4*)&colpart_s[3][c0];
  float4 rr = {p0.x + p1.x + p2.x + p3.x, p0.y + p1.y + p2.y + p3.y,
               p0.z + p1.z + p2.z + p3.z, p0.w + p1.w + p2.w + p3.w};
  *(float4*)(colpart + ((size_t)(bh * 16 + blk)) * 1024 + c0) = rr;
}

// ---------------- vsplit: colinv + V' = V*colinv (bf16 hi/lo, transposed) ---
__global__ __launch_bounds__(256) void vsplit(const float* __restrict__ colpart,
                                              const float* __restrict__ Vf,
                                              unsigned short* __restrict__ Vth,
                                              unsigned short* __restrict__ Vtl) {
  __shared__ float red[256];
  __shared__ float colinv_s[16];
  __shared__ unsigned short vh_s[32][16];
  __shared__ unsigned short vl_s[32][16];
  int tid = threadIdx.x;
  int flat = blockIdx.y * 64 + blockIdx.x;
  int nf = (flat & 7) * 384 + (flat >> 3);
  int bh = nf >> 6, mt = nf & 63;
  int b = bh / NH_, hd = bh % NH_;

  int p = tid >> 4, m16 = tid & 15;
  red[tid] = colpart[((size_t)(bh * 16 + p)) * 1024 + mt * 16 + m16];
  __syncthreads();
  #pragma unroll
  for (int st = 128; st >= 16; st >>= 1) {
    if (tid < st) red[tid] += red[tid + st];
    __syncthreads();
  }
  if (tid < 16) colinv_s[tid] = 1.0f / (red[tid] + 1e-8f);
  __syncthreads();
  if (tid < 128) {
    int m = tid >> 3, d4 = (tid & 7) * 4;
    float4 v = *(const float4*)(Vf + ((size_t)(b * N_ + mt * 16 + m)) * C_ +
                                hd * HD_ + d4);
    float ci = colinv_s[m];
    float va[4] = {v.x * ci, v.y * ci, v.z * ci, v.w * ci};
    #pragma unroll
    for (int i = 0; i < 4; ++i) {
      unsigned short h = f2bf(va[i]);
      vh_s[d4 + i][m] = h;
      vl_s[d4 + i][m] = f2bf(va[i] - bf2f(h));
    }
  }
  __syncthreads();
  if (tid < 64) {
    int d = tid >> 1, m8 = (tid & 1) * 8;
    uint4 h = *(uint4*)&vh_s[d][m8];
    *(uint4*)(Vth + ((size_t)bh * HD_ + d) * N_ + mt * 16 + m8) = h;
  } else if (tid < 128) {
    int t2 = tid - 64;
    int d = t2 >> 1, m8 = (t2 & 1) * 8;
    uint4 lo = *(uint4*)&vl_s[d][m8];
    *(uint4*)(Vtl + ((size_t)bh * HD_ + d) * N_ + mt * 16 + m8) = lo;
  }
}

// ---------------- pv3: recompute S, P=keep*exp, PV MFMA, epilogue *rinv -----
__global__ __launch_bounds__(256) void pv3(const unsigned short* __restrict__ Qh,
                                           const unsigned short* __restrict__ Ql,
                                           const unsigned short* __restrict__ Kh,
                                           const unsigned short* __restrict__ Kl,
                                           const unsigned short* __restrict__ Vth,
                                           const unsigned short* __restrict__ Vtl,
                                           const int* __restrict__ group,
                                           const float* __restrict__ rinv,
                                           unsigned short* __restrict__ aoh,
                                           unsigned short* __restrict__ aol) {
  __shared__ __align__(16) unsigned short kbufh[4096];   // [128kv][32d] swz
  __shared__ __align__(16) unsigned short kbufl[4096];
  __shared__ __align__(16) unsigned short vbufh[4096];   // [32d][128kv] swz
  __shared__ __align__(16) unsigned short vbufl[4096];
  __shared__ __align__(16) float bounce[4][512];         // [wave][16q][32kv] swz
  __shared__ int g_s[1024];
  int tid = threadIdx.x;
  int l = tid & 63, w = tid >> 6;
  int lanelo = l & 15, g16 = l >> 4;
  int flat = blockIdx.y * 16 + blockIdx.x;
  int nf = (flat & 7) * 96 + (flat >> 3);
  int bh = nf >> 4, blk = nf & 15;
  int b = bh / NH_, hd = bh % NH_;
  bool samehead = (hd < NH_ / 2);
  int q0 = blk * 64 + w * 16;
  size_t bhb = (size_t)bh * (N_ * HD_);

  *(int4*)&g_s[tid * 4] = *(const int4*)(group + b * N_ + tid * 4);
  bf16x8 aQh = *(const bf16x8*)(Qh + bhb + (size_t)(q0 + lanelo) * HD_ + g16 * 8);
  bf16x8 aQl = *(const bf16x8*)(Ql + bhb + (size_t)(q0 + lanelo) * HD_ + g16 * 8);
  float ri[4];
  #pragma unroll
  for (int t = 0; t < 4; ++t)
    ri[t] = rinv[(size_t)bh * N_ + q0 + g16 * 4 + t];
  __syncthreads();
  int gq[4];
  #pragma unroll
  for (int t = 0; t < 4; ++t) gq[t] = g_s[q0 + g16 * 4 + t];

  f32x4 o0 = {0.f, 0.f, 0.f, 0.f};   // rows x d[0..15]
  f32x4 o1 = {0.f, 0.f, 0.f, 0.f};   // rows x d[16..31]

  for (int ch = 0; ch < 8; ++ch) {
    __syncthreads();
    #pragma unroll
    for (int t2 = 0; t2 < 2; ++t2) {
      int f2 = t2 * 256 + tid;
      int row = f2 >> 2, c4 = f2 & 3;
      uint4 vh = *(const uint4*)(Kh + bhb + (size_t)(ch * 128 + row) * HD_ + c4 * 8);
      uint4 vl = *(const uint4*)(Kl + bhb + (size_t)(ch * 128 + row) * HD_ + c4 * 8);
      int phys = row * 64 + ((c4 ^ (row & 3)) << 4);
      *(uint4*)((char*)kbufh + phys) = vh;
      *(uint4*)((char*)kbufl + phys) = vl;
    }
    #pragma unroll
    for (int t2 = 0; t2 < 2; ++t2) {
      int f2 = t2 * 256 + tid;
      int d = f2 >> 4, c = f2 & 15;
      uint4 vh = *(const uint4*)(Vth + bhb + (size_t)d * N_ + ch * 128 + c * 8);
      uint4 vl = *(const uint4*)(Vtl + bhb + (size_t)d * N_ + ch * 128 + c * 8);
      int physc = c ^ (d & 15);
      *(uint4*)(vbufh + d * 128 + physc * 8) = vh;
      *(uint4*)(vbufl + d * 128 + physc * 8) = vl;
    }
    __syncthreads();

    #pragma unroll
    for (int pair = 0; pair < 4; ++pair) {     // 32 kv per pair
      f32x4 sa[2];
      #pragma unroll
      for (int half = 0; half < 2; ++half) {
        int kvl = pair * 32 + half * 16 + lanelo;
        int phys = kvl * 64 + ((g16 ^ (kvl & 3)) << 4);
        bf16x8 bh8 = *(const bf16x8*)((char*)kbufh + phys);
        bf16x8 bl8 = *(const bf16x8*)((char*)kbufl + phys);
        f32x4 acc = {0.f, 0.f, 0.f, 0.f};
        acc = __builtin_amdgcn_mfma_f32_16x16x32_bf16(aQh, bh8, acc, 0, 0, 0);
        acc = __builtin_amdgcn_mfma_f32_16x16x32_bf16(aQh, bl8, acc, 0, 0, 0);
        acc = __builtin_amdgcn_mfma_f32_16x16x32_bf16(aQl, bh8, acc, 0, 0, 0);
        sa[half] = acc;
      }
      #pragma unroll
      for (int half = 0; half < 2; ++half) {
        int kvloc = pair * 32 + half * 16 + lanelo;
        int gcol = g_s[ch * 128 + kvloc];
        int kv = half * 16 + lanelo;
        int chunk = kv >> 2;
        #pragma unroll
        for (int t = 0; t < 4; ++t) {
          bool keep = ((gcol == gq[t]) == samehead);
          float p = keep ? __expf(sa[half][t]) : 0.f;
          int q = g16 * 4 + t;
          bounce[w][q * 32 + ((chunk ^ (q & 7)) << 2) + (kv & 3)] = p;
        }
      }
      float pf[8];
      int q2 = lanelo;
      int c0i = (2 * g16) ^ (q2 & 7), c1i = (2 * g16 + 1) ^ (q2 & 7);
      *(float4*)&pf[0] = *(float4*)&bounce[w][q2 * 32 + c0i * 4];
      *(float4*)&pf[4] = *(float4*)&bounce[w][q2 * 32 + c1i * 4];
      bf16x8 pa;
      #pragma unroll
      for (int j = 0; j < 8; ++j) pa[j] = (short)f2bf(pf[j]);
      int vchunk = pair * 4 + g16;
      int d0 = lanelo, d1 = 16 + lanelo;
      bf16x8 v0h = *(const bf16x8*)(vbufh + d0 * 128 + ((vchunk ^ (d0 & 15)) << 3));
      bf16x8 v0l = *(const bf16x8*)(vbufl + d0 * 128 + ((vchunk ^ (d0 & 15)) << 3));
      bf16x8 v1h = *(const bf16x8*)(vbufh + d1 * 128 + ((vchunk ^ (d1 & 15)) << 3));
      bf16x8 v1l = *(const bf16x8*)(vbufl + d1 * 128 + ((vchunk ^ (d1 & 15)) << 3));
      o0 = __builtin_amdgcn_mfma_f32_16x16x32_bf16(pa, v0h, o0, 0, 0, 0);
      o0 = __builtin_amdgcn_mfma_f32_16x16x32_bf16(pa, v0l, o0, 0, 0, 0);
      o1 = __builtin_amdgcn_mfma_f32_16x16x32_bf16(pa, v1h, o1, 0, 0, 0);
      o1 = __builtin_amdgcn_mfma_f32_16x16x32_bf16(pa, v1l, o1, 0, 0, 0);
    }
  }
  #pragma unroll
  for (int t = 0; t < 4; ++t) {
    size_t row = (size_t)(b * N_ + q0 + g16 * 4 + t) * C_ + hd * HD_;
    float v0 = o0[t] * ri[t], v1 = o1[t] * ri[t];
    unsigned short h;
    h = f2bf(v0); aoh[row + lanelo]      = h; aol[row + lanelo]      = f2bf(v0 - bf2f(h));
    h = f2bf(v1); aoh[row + 16 + lanelo] = h; aol[row + 16 + lanelo] = f2bf(v1 - bf2f(h));
  }
}

// ---------------- launch ----------------------------------------------------
extern "C" void kernel_launch(void* const* d_in, const int* in_sizes, int n_in,
                              void* d_out, int out_size, void* d_ws, size_t ws_size,
                              hipStream_t stream) {
  const float* x     = (const float*)d_in[0];
  const float* Wqkv  = (const float*)d_in[1];
  const float* Wproj = (const float*)d_in[2];
  const float* Wgp   = (const float*)d_in[3];
  float* out = (float*)d_out;

  char* base = (char*)d_ws;
  size_t off = 0;
  auto alloc = [&](size_t bytes) {
    void* p = base + off;
    off += (bytes + 255) & ~(size_t)255;
    return p;
  };
  float*  Vf      = (float*)alloc(4096ull * C_ * 4);            // 6.3 MB
  float*  rinv    = (float*)alloc((size_t)BH_ * N_ * 4);
  float*  colpart = (float*)alloc((size_t)BH_ * 16 * N_ * 4);   // 3 MB
  double* Mgp     = (double*)alloc((size_t)GP_ * C_ * 8);
  int*    group   = (int*)alloc(4096ull * 4);
  unsigned short* xh  = (unsigned short*)alloc(4096ull * C_ * 2);
  unsigned short* xl  = (unsigned short*)alloc(4096ull * C_ * 2);
  unsigned short* Wqh = (unsigned short*)alloc((size_t)H3_ * C_ * 2);
  unsigned short* Wql = (unsigned short*)alloc((size_t)H3_ * C_ * 2);
  unsigned short* Wph = (unsigned short*)alloc((size_t)C_ * C_ * 2);
  unsigned short* Wpl = (unsigned short*)alloc((size_t)C_ * C_ * 2);
  unsigned short* aoh = (unsigned short*)alloc(4096ull * C_ * 2);
  unsigned short* aol = (unsigned short*)alloc(4096ull * C_ * 2);
  const size_t BSZ = (size_t)BH_ * N_ * HD_;
  unsigned short* Qh  = (unsigned short*)alloc(BSZ * 2);
  unsigned short* Ql  = (unsigned short*)alloc(BSZ * 2);
  unsigned short* Kh  = (unsigned short*)alloc(BSZ * 2);
  unsigned short* Kl  = (unsigned short*)alloc(BSZ * 2);
  unsigned short* Vth = (unsigned short*)alloc(BSZ * 2);
  unsigned short* Vtl = (unsigned short*)alloc(BSZ * 2);

  conv3<<<dim3(2112), 256, 0, stream>>>(x, Wqkv, Wproj, xh, xl, Wqh, Wql, Wph, Wpl);
  wgp_fuse<<<dim3(30), 256, 0, stream>>>(Wqkv, Wgp, Mgp);
  group_assign2<<<dim3(256), 320, 0, stream>>>(x, Mgp, group);
  gemm_qkv<<<dim3(576), 256, 0, stream>>>(xh, xl, Wqh, Wql,
                                          Qh, Ql, Kh, Kl, Vf);
  score3<<<dim3(16, BH_), 256, 0, stream>>>(Qh, Ql, Kh, Kl, group, rinv, colpart);
  vsplit<<<dim3(64, BH_), 256, 0, stream>>>(colpart, Vf, Vth, Vtl);
  pv3<<<dim3(16, BH_), 256, 0, stream>>>(Qh, Ql, Kh, Kl, Vth, Vtl, group,
                                         rinv, aoh, aol);
  gemm_proj<<<dim3(384), 256, 0, stream>>>(aoh, aol, Wph, Wpl, out);
}